// Round 1
// baseline (83423.688 us; speedup 1.0000x reference)
//
#include <hip/hip_runtime.h>
#include <stdint.h>

#define DEVFN __device__ __forceinline__
#define SCOPE_AGENT __HIP_MEMORY_SCOPE_AGENT

static constexpr int B_ = 16;
static constexpr int S_ = 1024;
static constexpr int FR = 128;     // FULL_RANGE
static constexpr int MU = 32;      // MOOD_UNITS
static constexpr int H_ = 512;     // UNITS
static constexpr int G4 = 2048;    // 4*H

DEVFN float blo(uint32_t w) { return __uint_as_float(w << 16); }
DEVFN float bhi(uint32_t w) { return __uint_as_float(w & 0xffff0000u); }
DEVFN uint32_t pack_bf16(float a, float b) {
    uint32_t ua = __float_as_uint(a); ua += 0x7fffu + ((ua >> 16) & 1u);
    uint32_t ub = __float_as_uint(b); ub += 0x7fffu + ((ub >> 16) & 1u);
    return (ua >> 16) | (ub & 0xffff0000u);
}
DEVFN float sigm(float x) { return 1.0f / (1.0f + __expf(-x)); }
DEVFN float tanhfast(float x) {
    float e = __expf(2.0f * fabsf(x));
    float r = 1.0f - 2.0f / (e + 1.0f);   // e==inf -> r=1
    return copysignf(r, x);
}

// ---------------------------------------------------------------------------
// mood: m = moods@W_mood.T + b_mood ; mc[b][row] = m@Wih0[:,128:160].T + bih0 + bhh0
// ---------------------------------------------------------------------------
__global__ __launch_bounds__(256) void mood_kernel(
    const float* __restrict__ moods, const float* __restrict__ W_mood,
    const float* __restrict__ b_mood, const float* __restrict__ W_ih0,
    const float* __restrict__ b_ih0, const float* __restrict__ b_hh0,
    float* __restrict__ mc)
{
    int b = blockIdx.x;            // 16
    int tid = threadIdx.x;         // 256
    __shared__ float m[MU];
    if (tid < MU) {
        float s = b_mood[tid];
        #pragma unroll
        for (int j = 0; j < 4; j++) s += moods[b * 4 + j] * W_mood[tid * 4 + j];
        m[tid] = s;
    }
    __syncthreads();
    for (int row = tid; row < G4; row += 256) {
        float s = b_ih0[row] + b_hh0[row];
        const float* w = W_ih0 + (size_t)row * (FR + MU) + FR;
        #pragma unroll
        for (int u = 0; u < MU; u++) s += m[u] * w[u];
        mc[(size_t)b * G4 + row] = s;
    }
}

// ---------------------------------------------------------------------------
// Persistent dilated-LSTM scan. 16 groups x 16 WGs x 512 threads.
// Group g owns SB=2^LAYER sub-batches; WG wgi owns hidden units [wgi*32, wgi*32+32).
// Weights live in registers (fp32 for layer 0, packed bf16 otherwise).
// Cross-WG sync: per-group monotonic counter, agent-scope relaxed atomics.
// ---------------------------------------------------------------------------
template <int LAYER>
__global__ __launch_bounds__(512) void scan_kernel(
    const float* __restrict__ x_in, float* __restrict__ x_out,
    const float* __restrict__ Wih, const float* __restrict__ Whh,
    const float* __restrict__ biasA, const float* __restrict__ biasB,
    float* __restrict__ h_buf, int* __restrict__ cnt)
{
    constexpr int DIL = 1 << LAYER;
    constexpr int SB = DIL;                 // sub-batches per group (16 groups)
    constexpr int T = S_ / DIL;
    constexpr int KIN = (LAYER == 0) ? FR : H_;
    constexpr int KW = KIN / 4;             // per-kg k-range for Wih
    constexpr int WIS = (LAYER == 0) ? (FR + MU) : H_;  // Wih row stride
    constexpr bool FP32W = (LAYER == 0);
    constexpr int HB = 16 * SB * H_;        // floats per h_buf phase

    const int bid = blockIdx.x;
    const int g = bid & 15;                 // group (same XCD under %8 round robin)
    const int wgi = bid >> 4;               // 0..15 : hidden-unit slice
    const int tid = threadIdx.x;
    const int kg = tid >> 7;                // 0..3 k-quadrant
    const int r = tid & 127;                // row within slice (gate*32+unit)
    const int U0 = wgi * 32;
    const int Rrow = (r >> 5) * H_ + U0 + (r & 31);  // global gate row
    const int sb0 = g * SB;

    __shared__ __align__(16) float lds_x[SB][KIN];
    __shared__ __align__(16) float lds_h[SB][H_];
    __shared__ float lds_p[SB][128 * 5];    // padded [128][5] partials

    int* cgrp = cnt + g;

    // ---- load weight slices into registers ----
    uint32_t whw[FP32W ? 1 : 64];
    float whwf[FP32W ? 128 : 1];
    uint32_t wiw[FP32W ? 1 : (KW / 2)];
    float wiwf[FP32W ? KW : 1];
    {
        const float* wr = Whh + (size_t)Rrow * H_ + kg * 128;
        if constexpr (FP32W) {
            #pragma unroll
            for (int j = 0; j < 128; j++) whwf[j] = wr[j];
        } else {
            #pragma unroll
            for (int j = 0; j < 64; j++) whw[j] = pack_bf16(wr[2 * j], wr[2 * j + 1]);
        }
        const float* wi = Wih + (size_t)Rrow * WIS + kg * KW;
        if constexpr (FP32W) {
            #pragma unroll
            for (int j = 0; j < KW; j++) wiwf[j] = wi[j];
        } else {
            #pragma unroll
            for (int j = 0; j < KW / 2; j++) wiw[j] = pack_bf16(wi[2 * j], wi[2 * j + 1]);
        }
    }

    // ---- per-update-thread bias + cell state ----
    const int b0 = tid >> 5, uu = tid & 31;
    float biasv[4] = {0.f, 0.f, 0.f, 0.f};
    float cst = 0.0f;
    if (tid < SB * 32) {
        #pragma unroll
        for (int Gx = 0; Gx < 4; Gx++) {
            int RR = Gx * H_ + U0 + uu;
            if constexpr (LAYER == 0)
                biasv[Gx] = biasA[(size_t)(sb0 + b0) * G4 + RR];   // mc (includes biases)
            else
                biasv[Gx] = biasA[RR] + biasB[RR];                 // bih + bhh
        }
    }

    float acc[SB];
    for (int t = 0; t < T; t++) {
        // ---- stage x_t for the group's sub-batches ----
        constexpr int XV = KIN / 4;
        for (int idx = tid; idx < SB * XV; idx += 512) {
            int b = idx / XV, j = idx - b * XV;
            int sb = sb0 + b, bg = sb >> LAYER, k = sb & (DIL - 1);
            const float4* src = (const float4*)(x_in + ((size_t)bg * S_ + (size_t)t * DIL + k) * KIN);
            *(float4*)&lds_x[b][4 * j] = src[j];
        }
        __syncthreads();

        // ---- x-part of gates (overlaps the barrier wait below) ----
        #pragma unroll
        for (int b = 0; b < SB; b++) {
            const float4* xp = (const float4*)&lds_x[b][kg * KW];
            float a = 0.f;
            if constexpr (FP32W) {
                #pragma unroll
                for (int j = 0; j < KW / 4; j++) {
                    float4 xv = xp[j];
                    a = fmaf(wiwf[4 * j + 0], xv.x, a); a = fmaf(wiwf[4 * j + 1], xv.y, a);
                    a = fmaf(wiwf[4 * j + 2], xv.z, a); a = fmaf(wiwf[4 * j + 3], xv.w, a);
                }
            } else {
                #pragma unroll
                for (int j = 0; j < KW / 4; j++) {
                    float4 xv = xp[j];
                    uint32_t w0 = wiw[2 * j], w1 = wiw[2 * j + 1];
                    a = fmaf(blo(w0), xv.x, a); a = fmaf(bhi(w0), xv.y, a);
                    a = fmaf(blo(w1), xv.z, a); a = fmaf(bhi(w1), xv.w, a);
                }
            }
            acc[b] = a;
        }

        // ---- wait for h_{t-1}, then recurrent part ----
        if (t > 0) {
            if (tid == 0) {
                int target = 16 * t;
                while (__hip_atomic_load(cgrp, __ATOMIC_RELAXED, SCOPE_AGENT) < target)
                    __builtin_amdgcn_s_sleep(1);
            }
            __syncthreads();
            float* hrd = h_buf + (size_t)((t - 1) & 1) * HB + (size_t)sb0 * H_;
            for (int idx = tid; idx < SB * H_; idx += 512) {
                lds_h[idx >> 9][idx & 511] =
                    __hip_atomic_load(hrd + idx, __ATOMIC_RELAXED, SCOPE_AGENT);
            }
            __syncthreads();
            #pragma unroll
            for (int b = 0; b < SB; b++) {
                const float4* hp = (const float4*)&lds_h[b][kg * 128];
                float a = acc[b];
                if constexpr (FP32W) {
                    #pragma unroll
                    for (int j = 0; j < 32; j++) {
                        float4 hv = hp[j];
                        a = fmaf(whwf[4 * j + 0], hv.x, a); a = fmaf(whwf[4 * j + 1], hv.y, a);
                        a = fmaf(whwf[4 * j + 2], hv.z, a); a = fmaf(whwf[4 * j + 3], hv.w, a);
                    }
                } else {
                    #pragma unroll
                    for (int j = 0; j < 32; j++) {
                        float4 hv = hp[j];
                        uint32_t w0 = whw[2 * j], w1 = whw[2 * j + 1];
                        a = fmaf(blo(w0), hv.x, a); a = fmaf(bhi(w0), hv.y, a);
                        a = fmaf(blo(w1), hv.z, a); a = fmaf(bhi(w1), hv.w, a);
                    }
                }
                acc[b] = a;
            }
        }

        // ---- reduce partials across the 4 k-quadrants ----
        #pragma unroll
        for (int b = 0; b < SB; b++) lds_p[b][r * 5 + kg] = acc[b];
        __syncthreads();

        // ---- gate nonlinearity + cell/hidden update (SB*32 threads) ----
        if (tid < SB * 32) {
            float gv[4];
            #pragma unroll
            for (int Gx = 0; Gx < 4; Gx++) {
                int rr = Gx * 32 + uu;
                gv[Gx] = lds_p[b0][rr * 5 + 0] + lds_p[b0][rr * 5 + 1] +
                         lds_p[b0][rr * 5 + 2] + lds_p[b0][rr * 5 + 3] + biasv[Gx];
            }
            float ci = sigm(gv[0]), cf = sigm(gv[1]);
            float cg = tanhfast(gv[2]), co = sigm(gv[3]);
            cst = cf * cst + ci * cg;
            float hv = co * tanhfast(cst);
            int sb = sb0 + b0, bg = sb >> LAYER, k = sb & (DIL - 1);
            __hip_atomic_store(h_buf + (size_t)(t & 1) * HB + (size_t)sb * H_ + U0 + uu,
                               hv, __ATOMIC_RELAXED, SCOPE_AGENT);
            float res;
            if constexpr (LAYER > 0) res = lds_x[b0][U0 + uu]; else res = 0.f;
            x_out[((size_t)bg * S_ + (size_t)t * DIL + k) * H_ + U0 + uu] = hv + res;
        }
        asm volatile("s_waitcnt vmcnt(0)" ::: "memory");
        __syncthreads();   // drains all waves' stores before the arrive
        if (tid == 0)
            __hip_atomic_fetch_add(cgrp, 1, __ATOMIC_RELAXED, SCOPE_AGENT);
    }
}

// ---------------------------------------------------------------------------
// out = x4 @ W_out.T + b_out   ([16384,512] x [512,128])
// block: 8 tokens x 128 cols, x rows staged in LDS
// ---------------------------------------------------------------------------
__global__ __launch_bounds__(256) void out_gemm(
    const float* __restrict__ x, const float* __restrict__ Wout,
    const float* __restrict__ bout, float* __restrict__ out)
{
    __shared__ __align__(16) float xs[8][H_];
    int tid = threadIdx.x;
    size_t tok0 = (size_t)blockIdx.x * 8;
    const float4* src = (const float4*)(x + tok0 * H_);
    for (int idx = tid; idx < 8 * H_ / 4; idx += 256)
        ((float4*)xs)[idx] = src[idx];
    __syncthreads();

    int col = tid & 127, th = tid >> 7;  // th: 0/1 -> tokens [0..3] / [4..7]
    int tb = th * 4;
    float a0 = 0.f, a1 = 0.f, a2 = 0.f, a3 = 0.f;
    const float4* w = (const float4*)(Wout + (size_t)col * H_);
    #pragma unroll 4
    for (int j = 0; j < H_ / 4; j++) {
        float4 wv = w[j];
        float4 x0 = ((const float4*)xs[tb + 0])[j];
        float4 x1 = ((const float4*)xs[tb + 1])[j];
        float4 x2 = ((const float4*)xs[tb + 2])[j];
        float4 x3 = ((const float4*)xs[tb + 3])[j];
        a0 = fmaf(wv.x, x0.x, a0); a0 = fmaf(wv.y, x0.y, a0); a0 = fmaf(wv.z, x0.z, a0); a0 = fmaf(wv.w, x0.w, a0);
        a1 = fmaf(wv.x, x1.x, a1); a1 = fmaf(wv.y, x1.y, a1); a1 = fmaf(wv.z, x1.z, a1); a1 = fmaf(wv.w, x1.w, a1);
        a2 = fmaf(wv.x, x2.x, a2); a2 = fmaf(wv.y, x2.y, a2); a2 = fmaf(wv.z, x2.z, a2); a2 = fmaf(wv.w, x2.w, a2);
        a3 = fmaf(wv.x, x3.x, a3); a3 = fmaf(wv.y, x3.y, a3); a3 = fmaf(wv.z, x3.z, a3); a3 = fmaf(wv.w, x3.w, a3);
    }
    float bo = bout[col];
    out[(tok0 + tb + 0) * FR + col] = a0 + bo;
    out[(tok0 + tb + 1) * FR + col] = a1 + bo;
    out[(tok0 + tb + 2) * FR + col] = a2 + bo;
    out[(tok0 + tb + 3) * FR + col] = a3 + bo;
}

// ---------------------------------------------------------------------------
extern "C" void kernel_launch(void* const* d_in, const int* in_sizes, int n_in,
                              void* d_out, int out_size, void* d_ws, size_t ws_size,
                              hipStream_t stream)
{
    const float* inputs = (const float*)d_in[0];
    const float* moods  = (const float*)d_in[1];
    const float* W_mood = (const float*)d_in[2];
    const float* b_mood = (const float*)d_in[3];
    const float* W_ih0  = (const float*)d_in[4];
    const float* W_hh0  = (const float*)d_in[5];
    const float* b_ih0  = (const float*)d_in[6];
    const float* b_hh0  = (const float*)d_in[7];
    const float* W_ih_r = (const float*)d_in[8];
    const float* W_hh_r = (const float*)d_in[9];
    const float* b_ih_r = (const float*)d_in[10];
    const float* b_hh_r = (const float*)d_in[11];
    const float* W_out  = (const float*)d_in[12];
    const float* b_out  = (const float*)d_in[13];

    float* ws = (float*)d_ws;
    float* mc = ws;                          // 16*2048        = 32768
    float* xA = ws + 32768;                  // 16*1024*512    = 8388608
    float* xB = xA + 8388608;
    float* hb = xB + 8388608;                // 2*128*512      = 131072
    int*  cnt = (int*)(hb + 131072);         // 64 ints (4 layers x 16 groups)

    hipMemsetAsync(cnt, 0, 64 * sizeof(int), stream);
    mood_kernel<<<16, 256, 0, stream>>>(moods, W_mood, b_mood, W_ih0, b_ih0, b_hh0, mc);

    scan_kernel<0><<<256, 512, 0, stream>>>(inputs, xA, W_ih0, W_hh0, mc, nullptr, hb, cnt);
    scan_kernel<1><<<256, 512, 0, stream>>>(xA, xB, W_ih_r, W_hh_r,
                                            b_ih_r, b_hh_r, hb, cnt + 16);
    scan_kernel<2><<<256, 512, 0, stream>>>(xB, xA, W_ih_r + (size_t)G4 * H_,
                                            W_hh_r + (size_t)G4 * H_,
                                            b_ih_r + G4, b_hh_r + G4, hb, cnt + 32);
    scan_kernel<3><<<256, 512, 0, stream>>>(xA, xB, W_ih_r + (size_t)2 * G4 * H_,
                                            W_hh_r + (size_t)2 * G4 * H_,
                                            b_ih_r + 2 * G4, b_hh_r + 2 * G4, hb, cnt + 48);

    out_gemm<<<2048, 256, 0, stream>>>(xB, W_out, b_out, (float*)d_out);
}

// Round 2
// 80632.770 us; speedup vs baseline: 1.0346x; 1.0346x over previous
//
#include <hip/hip_runtime.h>
#include <stdint.h>

#define DEVFN __device__ __forceinline__
#define SCOPE_AGENT __HIP_MEMORY_SCOPE_AGENT

static constexpr int B_ = 16;
static constexpr int S_ = 1024;
static constexpr int FR = 128;     // FULL_RANGE
static constexpr int MU = 32;      // MOOD_UNITS
static constexpr int H_ = 512;     // UNITS
static constexpr int G4 = 2048;    // 4*H

// counters: one per group, padded to 32 ints (128 B) to kill line contention
static constexpr int CNT_STRIDE = 32;
static constexpr int CNT_PER_LAYER = 16 * CNT_STRIDE;   // 512 ints per layer

DEVFN float blo(uint32_t w) { return __uint_as_float(w << 16); }
DEVFN float bhi(uint32_t w) { return __uint_as_float(w & 0xffff0000u); }
DEVFN uint32_t pack_bf16(float a, float b) {
    uint32_t ua = __float_as_uint(a); ua += 0x7fffu + ((ua >> 16) & 1u);
    uint32_t ub = __float_as_uint(b); ub += 0x7fffu + ((ub >> 16) & 1u);
    return (ua >> 16) | (ub & 0xffff0000u);
}
DEVFN float sigm(float x) { return 1.0f / (1.0f + __expf(-x)); }
DEVFN float tanhfast(float x) {
    float e = __expf(2.0f * fabsf(x));
    float r = 1.0f - 2.0f / (e + 1.0f);   // e==inf -> r=1
    return copysignf(r, x);
}

// ---------------------------------------------------------------------------
// mood: m = moods@W_mood.T + b_mood ; mc[b][row] = m@Wih0[:,128:160].T + bih0 + bhh0
// ---------------------------------------------------------------------------
__global__ __launch_bounds__(256) void mood_kernel(
    const float* __restrict__ moods, const float* __restrict__ W_mood,
    const float* __restrict__ b_mood, const float* __restrict__ W_ih0,
    const float* __restrict__ b_ih0, const float* __restrict__ b_hh0,
    float* __restrict__ mc)
{
    int b = blockIdx.x;            // 16
    int tid = threadIdx.x;         // 256
    __shared__ float m[MU];
    if (tid < MU) {
        float s = b_mood[tid];
        #pragma unroll
        for (int j = 0; j < 4; j++) s += moods[b * 4 + j] * W_mood[tid * 4 + j];
        m[tid] = s;
    }
    __syncthreads();
    for (int row = tid; row < G4; row += 256) {
        float s = b_ih0[row] + b_hh0[row];
        const float* w = W_ih0 + (size_t)row * (FR + MU) + FR;
        #pragma unroll
        for (int u = 0; u < MU; u++) s += m[u] * w[u];
        mc[(size_t)b * G4 + row] = s;
    }
}

// ---------------------------------------------------------------------------
// Persistent dilated-LSTM scan. 16 groups x 16 WGs x 512 threads.
// Group g owns SB=2^LAYER sub-batches; WG wgi owns hidden units [wgi*32, wgi*32+32).
// Weights live in registers (fp32 for layer 0, packed bf16 otherwise).
// __launch_bounds__(512, 2): 2 waves/EU min -> 256-VGPR cap, NO spill.
// (R1 failure: default cap of 128 VGPRs spilled all weights to scratch ->
//  40-55 GB FETCH_SIZE per dispatch, 60-170 us/step.)
// Cross-WG sync: per-group monotonic counter, agent-scope relaxed atomics.
// ---------------------------------------------------------------------------
template <int LAYER>
__global__ __launch_bounds__(512, 2) void scan_kernel(
    const float* __restrict__ x_in, float* __restrict__ x_out,
    const float* __restrict__ Wih, const float* __restrict__ Whh,
    const float* __restrict__ biasA, const float* __restrict__ biasB,
    float* __restrict__ h_buf, int* __restrict__ cnt)
{
    constexpr int DIL = 1 << LAYER;
    constexpr int SB = DIL;                 // sub-batches per group (16 groups)
    constexpr int T = S_ / DIL;
    constexpr int KIN = (LAYER == 0) ? FR : H_;
    constexpr int KW = KIN / 4;             // per-kg k-range for Wih
    constexpr int WIS = (LAYER == 0) ? (FR + MU) : H_;  // Wih row stride
    constexpr bool FP32W = (LAYER == 0);
    constexpr int HB = 16 * SB * H_;        // floats per h_buf phase

    const int bid = blockIdx.x;
    const int g = bid & 15;                 // group (same XCD under %8 round robin)
    const int wgi = bid >> 4;               // 0..15 : hidden-unit slice
    const int tid = threadIdx.x;
    const int kg = tid >> 7;                // 0..3 k-quadrant
    const int r = tid & 127;                // row within slice (gate*32+unit)
    const int U0 = wgi * 32;
    const int Rrow = (r >> 5) * H_ + U0 + (r & 31);  // global gate row
    const int sb0 = g * SB;

    __shared__ __align__(16) float lds_x[SB][KIN];
    __shared__ __align__(16) float lds_h[SB][H_];
    __shared__ float lds_p[SB][128 * 5];    // padded [128][5] partials

    int* cgrp = cnt + g * CNT_STRIDE;

    // ---- load weight slices into registers ----
    uint32_t whw[FP32W ? 1 : 64];
    float whwf[FP32W ? 128 : 1];
    uint32_t wiw[FP32W ? 1 : (KW / 2)];
    float wiwf[FP32W ? KW : 1];
    {
        const float* wr = Whh + (size_t)Rrow * H_ + kg * 128;
        if constexpr (FP32W) {
            #pragma unroll
            for (int j = 0; j < 128; j++) whwf[j] = wr[j];
        } else {
            #pragma unroll
            for (int j = 0; j < 64; j++) whw[j] = pack_bf16(wr[2 * j], wr[2 * j + 1]);
        }
        const float* wi = Wih + (size_t)Rrow * WIS + kg * KW;
        if constexpr (FP32W) {
            #pragma unroll
            for (int j = 0; j < KW; j++) wiwf[j] = wi[j];
        } else {
            #pragma unroll
            for (int j = 0; j < KW / 2; j++) wiw[j] = pack_bf16(wi[2 * j], wi[2 * j + 1]);
        }
    }

    // ---- per-update-thread bias + cell state ----
    const int b0 = tid >> 5, uu = tid & 31;
    float biasv[4] = {0.f, 0.f, 0.f, 0.f};
    float cst = 0.0f;
    if (tid < SB * 32) {
        #pragma unroll
        for (int Gx = 0; Gx < 4; Gx++) {
            int RR = Gx * H_ + U0 + uu;
            if constexpr (LAYER == 0)
                biasv[Gx] = biasA[(size_t)(sb0 + b0) * G4 + RR];   // mc (includes biases)
            else
                biasv[Gx] = biasA[RR] + biasB[RR];                 // bih + bhh
        }
    }

    float acc[SB];
    for (int t = 0; t < T; t++) {
        // ---- stage x_t for the group's sub-batches ----
        constexpr int XV = KIN / 4;
        for (int idx = tid; idx < SB * XV; idx += 512) {
            int b = idx / XV, j = idx - b * XV;
            int sb = sb0 + b, bg = sb >> LAYER, k = sb & (DIL - 1);
            const float4* src = (const float4*)(x_in + ((size_t)bg * S_ + (size_t)t * DIL + k) * KIN);
            *(float4*)&lds_x[b][4 * j] = src[j];
        }
        __syncthreads();

        // ---- x-part of gates (overlaps the barrier wait below) ----
        #pragma unroll
        for (int b = 0; b < SB; b++) {
            const float4* xp = (const float4*)&lds_x[b][kg * KW];
            float a = 0.f;
            if constexpr (FP32W) {
                #pragma unroll
                for (int j = 0; j < KW / 4; j++) {
                    float4 xv = xp[j];
                    a = fmaf(wiwf[4 * j + 0], xv.x, a); a = fmaf(wiwf[4 * j + 1], xv.y, a);
                    a = fmaf(wiwf[4 * j + 2], xv.z, a); a = fmaf(wiwf[4 * j + 3], xv.w, a);
                }
            } else {
                #pragma unroll
                for (int j = 0; j < KW / 4; j++) {
                    float4 xv = xp[j];
                    uint32_t w0 = wiw[2 * j], w1 = wiw[2 * j + 1];
                    a = fmaf(blo(w0), xv.x, a); a = fmaf(bhi(w0), xv.y, a);
                    a = fmaf(blo(w1), xv.z, a); a = fmaf(bhi(w1), xv.w, a);
                }
            }
            acc[b] = a;
        }

        // ---- wait for h_{t-1}, then recurrent part ----
        if (t > 0) {
            if (tid == 0) {
                int target = 16 * t;
                while (__hip_atomic_load(cgrp, __ATOMIC_RELAXED, SCOPE_AGENT) < target)
                    __builtin_amdgcn_s_sleep(1);
            }
            __syncthreads();
            float* hrd = h_buf + (size_t)((t - 1) & 1) * HB + (size_t)sb0 * H_;
            for (int idx = tid; idx < SB * H_; idx += 512) {
                lds_h[idx >> 9][idx & 511] =
                    __hip_atomic_load(hrd + idx, __ATOMIC_RELAXED, SCOPE_AGENT);
            }
            __syncthreads();
            #pragma unroll
            for (int b = 0; b < SB; b++) {
                const float4* hp = (const float4*)&lds_h[b][kg * 128];
                float a = acc[b];
                if constexpr (FP32W) {
                    #pragma unroll
                    for (int j = 0; j < 32; j++) {
                        float4 hv = hp[j];
                        a = fmaf(whwf[4 * j + 0], hv.x, a); a = fmaf(whwf[4 * j + 1], hv.y, a);
                        a = fmaf(whwf[4 * j + 2], hv.z, a); a = fmaf(whwf[4 * j + 3], hv.w, a);
                    }
                } else {
                    #pragma unroll
                    for (int j = 0; j < 32; j++) {
                        float4 hv = hp[j];
                        uint32_t w0 = whw[2 * j], w1 = whw[2 * j + 1];
                        a = fmaf(blo(w0), hv.x, a); a = fmaf(bhi(w0), hv.y, a);
                        a = fmaf(blo(w1), hv.z, a); a = fmaf(bhi(w1), hv.w, a);
                    }
                }
                acc[b] = a;
            }
        }

        // ---- reduce partials across the 4 k-quadrants ----
        #pragma unroll
        for (int b = 0; b < SB; b++) lds_p[b][r * 5 + kg] = acc[b];
        __syncthreads();

        // ---- gate nonlinearity + cell/hidden update (SB*32 threads) ----
        if (tid < SB * 32) {
            float gv[4];
            #pragma unroll
            for (int Gx = 0; Gx < 4; Gx++) {
                int rr = Gx * 32 + uu;
                gv[Gx] = lds_p[b0][rr * 5 + 0] + lds_p[b0][rr * 5 + 1] +
                         lds_p[b0][rr * 5 + 2] + lds_p[b0][rr * 5 + 3] + biasv[Gx];
            }
            float ci = sigm(gv[0]), cf = sigm(gv[1]);
            float cg = tanhfast(gv[2]), co = sigm(gv[3]);
            cst = cf * cst + ci * cg;
            float hv = co * tanhfast(cst);
            int sb = sb0 + b0, bg = sb >> LAYER, k = sb & (DIL - 1);
            __hip_atomic_store(h_buf + (size_t)(t & 1) * HB + (size_t)sb * H_ + U0 + uu,
                               hv, __ATOMIC_RELAXED, SCOPE_AGENT);
            float res;
            if constexpr (LAYER > 0) res = lds_x[b0][U0 + uu]; else res = 0.f;
            x_out[((size_t)bg * S_ + (size_t)t * DIL + k) * H_ + U0 + uu] = hv + res;
        }
        asm volatile("s_waitcnt vmcnt(0)" ::: "memory");
        __syncthreads();   // drains all waves' stores before the arrive
        if (tid == 0)
            __hip_atomic_fetch_add(cgrp, 1, __ATOMIC_RELAXED, SCOPE_AGENT);
    }
}

// ---------------------------------------------------------------------------
// out = x4 @ W_out.T + b_out   ([16384,512] x [512,128])
// block: 8 tokens x 128 cols, x rows staged in LDS
// ---------------------------------------------------------------------------
__global__ __launch_bounds__(256) void out_gemm(
    const float* __restrict__ x, const float* __restrict__ Wout,
    const float* __restrict__ bout, float* __restrict__ out)
{
    __shared__ __align__(16) float xs[8][H_];
    int tid = threadIdx.x;
    size_t tok0 = (size_t)blockIdx.x * 8;
    const float4* src = (const float4*)(x + tok0 * H_);
    for (int idx = tid; idx < 8 * H_ / 4; idx += 256)
        ((float4*)xs)[idx] = src[idx];
    __syncthreads();

    int col = tid & 127, th = tid >> 7;  // th: 0/1 -> tokens [0..3] / [4..7]
    int tb = th * 4;
    float a0 = 0.f, a1 = 0.f, a2 = 0.f, a3 = 0.f;
    const float4* w = (const float4*)(Wout + (size_t)col * H_);
    #pragma unroll 4
    for (int j = 0; j < H_ / 4; j++) {
        float4 wv = w[j];
        float4 x0 = ((const float4*)xs[tb + 0])[j];
        float4 x1 = ((const float4*)xs[tb + 1])[j];
        float4 x2 = ((const float4*)xs[tb + 2])[j];
        float4 x3 = ((const float4*)xs[tb + 3])[j];
        a0 = fmaf(wv.x, x0.x, a0); a0 = fmaf(wv.y, x0.y, a0); a0 = fmaf(wv.z, x0.z, a0); a0 = fmaf(wv.w, x0.w, a0);
        a1 = fmaf(wv.x, x1.x, a1); a1 = fmaf(wv.y, x1.y, a1); a1 = fmaf(wv.z, x1.z, a1); a1 = fmaf(wv.w, x1.w, a1);
        a2 = fmaf(wv.x, x2.x, a2); a2 = fmaf(wv.y, x2.y, a2); a2 = fmaf(wv.z, x2.z, a2); a2 = fmaf(wv.w, x2.w, a2);
        a3 = fmaf(wv.x, x3.x, a3); a3 = fmaf(wv.y, x3.y, a3); a3 = fmaf(wv.z, x3.z, a3); a3 = fmaf(wv.w, x3.w, a3);
    }
    float bo = bout[col];
    out[(tok0 + tb + 0) * FR + col] = a0 + bo;
    out[(tok0 + tb + 1) * FR + col] = a1 + bo;
    out[(tok0 + tb + 2) * FR + col] = a2 + bo;
    out[(tok0 + tb + 3) * FR + col] = a3 + bo;
}

// ---------------------------------------------------------------------------
extern "C" void kernel_launch(void* const* d_in, const int* in_sizes, int n_in,
                              void* d_out, int out_size, void* d_ws, size_t ws_size,
                              hipStream_t stream)
{
    const float* inputs = (const float*)d_in[0];
    const float* moods  = (const float*)d_in[1];
    const float* W_mood = (const float*)d_in[2];
    const float* b_mood = (const float*)d_in[3];
    const float* W_ih0  = (const float*)d_in[4];
    const float* W_hh0  = (const float*)d_in[5];
    const float* b_ih0  = (const float*)d_in[6];
    const float* b_hh0  = (const float*)d_in[7];
    const float* W_ih_r = (const float*)d_in[8];
    const float* W_hh_r = (const float*)d_in[9];
    const float* b_ih_r = (const float*)d_in[10];
    const float* b_hh_r = (const float*)d_in[11];
    const float* W_out  = (const float*)d_in[12];
    const float* b_out  = (const float*)d_in[13];

    float* ws = (float*)d_ws;
    float* mc = ws;                          // 16*2048        = 32768
    float* xA = ws + 32768;                  // 16*1024*512    = 8388608
    float* xB = xA + 8388608;
    float* hb = xB + 8388608;                // 2*128*512      = 131072
    int*  cnt = (int*)(hb + 131072);         // 4 layers x 16 groups x 32-int pad

    hipMemsetAsync(cnt, 0, 4 * CNT_PER_LAYER * sizeof(int), stream);
    mood_kernel<<<16, 256, 0, stream>>>(moods, W_mood, b_mood, W_ih0, b_ih0, b_hh0, mc);

    scan_kernel<0><<<256, 512, 0, stream>>>(inputs, xA, W_ih0, W_hh0, mc, nullptr, hb, cnt);
    scan_kernel<1><<<256, 512, 0, stream>>>(xA, xB, W_ih_r, W_hh_r,
                                            b_ih_r, b_hh_r, hb, cnt + CNT_PER_LAYER);
    scan_kernel<2><<<256, 512, 0, stream>>>(xB, xA, W_ih_r + (size_t)G4 * H_,
                                            W_hh_r + (size_t)G4 * H_,
                                            b_ih_r + G4, b_hh_r + G4, hb, cnt + 2 * CNT_PER_LAYER);
    scan_kernel<3><<<256, 512, 0, stream>>>(xA, xB, W_ih_r + (size_t)2 * G4 * H_,
                                            W_hh_r + (size_t)2 * G4 * H_,
                                            b_ih_r + 2 * G4, b_hh_r + 2 * G4, hb, cnt + 3 * CNT_PER_LAYER);

    out_gemm<<<2048, 256, 0, stream>>>(xB, W_out, b_out, (float*)d_out);
}

// Round 3
// 60938.904 us; speedup vs baseline: 1.3690x; 1.3232x over previous
//
#include <hip/hip_runtime.h>
#include <stdint.h>

#define DEVFN __device__ __forceinline__
#define SCOPE_AGENT __HIP_MEMORY_SCOPE_AGENT

static constexpr int B_ = 16;
static constexpr int S_ = 1024;
static constexpr int FR = 128;     // FULL_RANGE
static constexpr int MU = 32;      // MOOD_UNITS
static constexpr int H_ = 512;     // UNITS
static constexpr int G4 = 2048;    // 4*H

// counters: one per group, padded to 32 ints (128 B) to kill line contention
static constexpr int CNT_STRIDE = 32;
static constexpr int CNT_PER_LAYER = 16 * CNT_STRIDE;   // 512 ints per layer

// Weights as ext_vector_type values: SSA vectors the regalloc MUST keep in
// VGPRs. (R1/R2 failure: uint32_t w[64] / float w[128] allocas are too big
// for SROA -> lived in scratch; VGPR_Count stayed 128 and FETCH_SIZE was
// 40-55 GB/dispatch of spill re-reads.)
typedef float    f32x16 __attribute__((ext_vector_type(16)));
typedef uint32_t u32x16 __attribute__((ext_vector_type(16)));

DEVFN float blo(uint32_t w) { return __uint_as_float(w << 16); }
DEVFN float bhi(uint32_t w) { return __uint_as_float(w & 0xffff0000u); }
DEVFN uint32_t pack_bf16(float a, float b) {
    uint32_t ua = __float_as_uint(a); ua += 0x7fffu + ((ua >> 16) & 1u);
    uint32_t ub = __float_as_uint(b); ub += 0x7fffu + ((ub >> 16) & 1u);
    return (ua >> 16) | (ub & 0xffff0000u);
}
DEVFN float sigm(float x) { return 1.0f / (1.0f + __expf(-x)); }
DEVFN float tanhfast(float x) {
    float e = __expf(2.0f * fabsf(x));
    float r = 1.0f - 2.0f / (e + 1.0f);   // e==inf -> r=1
    return copysignf(r, x);
}

// 16 packed pairs (32 bf16 weights) . 8 float4 (32 inputs)
DEVFN float dot32(u32x16 w, const float4* __restrict__ p) {
    float a = 0.f;
    #pragma unroll
    for (int j = 0; j < 8; j++) {
        uint32_t w0 = w[2 * j], w1 = w[2 * j + 1];
        float4 v = p[j];
        a = fmaf(blo(w0), v.x, a); a = fmaf(bhi(w0), v.y, a);
        a = fmaf(blo(w1), v.z, a); a = fmaf(bhi(w1), v.w, a);
    }
    return a;
}
// 16 fp32 weights . 4 float4 (16 inputs)
DEVFN float dotf(f32x16 w, const float4* __restrict__ p) {
    float a = 0.f;
    #pragma unroll
    for (int j = 0; j < 4; j++) {
        float4 v = p[j];
        a = fmaf(w[4 * j + 0], v.x, a); a = fmaf(w[4 * j + 1], v.y, a);
        a = fmaf(w[4 * j + 2], v.z, a); a = fmaf(w[4 * j + 3], v.w, a);
    }
    return a;
}
DEVFN u32x16 load_pack32(const float* __restrict__ p) {
    u32x16 v;
    #pragma unroll
    for (int j = 0; j < 16; j++) v[j] = pack_bf16(p[2 * j], p[2 * j + 1]);
    return v;
}
DEVFN f32x16 load_f16v(const float* __restrict__ p) {
    f32x16 v;
    #pragma unroll
    for (int j = 0; j < 16; j++) v[j] = p[j];
    return v;
}

// ---------------------------------------------------------------------------
// mood: m = moods@W_mood.T + b_mood ; mc[b][row] = m@Wih0[:,128:160].T + bih0 + bhh0
// ---------------------------------------------------------------------------
__global__ __launch_bounds__(256) void mood_kernel(
    const float* __restrict__ moods, const float* __restrict__ W_mood,
    const float* __restrict__ b_mood, const float* __restrict__ W_ih0,
    const float* __restrict__ b_ih0, const float* __restrict__ b_hh0,
    float* __restrict__ mc)
{
    int b = blockIdx.x;            // 16
    int tid = threadIdx.x;         // 256
    __shared__ float m[MU];
    if (tid < MU) {
        float s = b_mood[tid];
        #pragma unroll
        for (int j = 0; j < 4; j++) s += moods[b * 4 + j] * W_mood[tid * 4 + j];
        m[tid] = s;
    }
    __syncthreads();
    for (int row = tid; row < G4; row += 256) {
        float s = b_ih0[row] + b_hh0[row];
        const float* w = W_ih0 + (size_t)row * (FR + MU) + FR;
        #pragma unroll
        for (int u = 0; u < MU; u++) s += m[u] * w[u];
        mc[(size_t)b * G4 + row] = s;
    }
}

// ---------------------------------------------------------------------------
// Persistent dilated-LSTM scan. 16 groups x 16 WGs x 512 threads.
// Group g owns SB=2^LAYER sub-batches; WG wgi owns hidden units [wgi*32, wgi*32+32).
// Weights in ext_vector registers (fp32 for layer 0, packed bf16 otherwise).
// Cross-WG sync: per-group monotonic counter, agent-scope relaxed atomics.
// Group members are bid%16==g -> same XCD under round-robin -> same L2.
// ---------------------------------------------------------------------------
template <int LAYER>
__global__ __launch_bounds__(512, 2) void scan_kernel(
    const float* __restrict__ x_in, float* __restrict__ x_out,
    const float* __restrict__ Wih, const float* __restrict__ Whh,
    const float* __restrict__ biasA, const float* __restrict__ biasB,
    float* __restrict__ h_buf, int* __restrict__ cnt)
{
    constexpr int DIL = 1 << LAYER;
    constexpr int SB = DIL;                 // sub-batches per group (16 groups)
    constexpr int T = S_ / DIL;
    constexpr int KIN = (LAYER == 0) ? FR : H_;
    constexpr int KW = KIN / 4;             // per-kg k-range for Wih
    constexpr int WIS = (LAYER == 0) ? (FR + MU) : H_;  // Wih row stride
    constexpr bool FP32W = (LAYER == 0);
    constexpr int HB = 16 * SB * H_;        // floats per h_buf phase

    const int bid = blockIdx.x;
    const int g = bid & 15;                 // group
    const int wgi = bid >> 4;               // 0..15 : hidden-unit slice
    const int tid = threadIdx.x;
    const int kg = tid >> 7;                // 0..3 k-quadrant
    const int r = tid & 127;                // row within slice (gate*32+unit)
    const int U0 = wgi * 32;
    const int Rrow = (r >> 5) * H_ + U0 + (r & 31);  // global gate row
    const int sb0 = g * SB;

    __shared__ __align__(16) float lds_x[SB][KIN];
    __shared__ __align__(16) float lds_h[SB][H_];
    __shared__ float lds_p[SB][128 * 5];    // padded [128][5] partials

    int* cgrp = cnt + g * CNT_STRIDE;

    // ---- weight slices as register vectors ----
    // layers 1-3 (bf16-packed): 4+4 u32x16 = 128 VGPRs
    u32x16 whA, whB, whC, whD, wiA, wiB, wiC, wiD;
    // layer 0 (fp32): 8+2 f32x16 = 160 VGPRs
    f32x16 wf0, wf1, wf2, wf3, wf4, wf5, wf6, wf7, wx0, wx1;
    {
        const float* wr = Whh + (size_t)Rrow * H_ + kg * 128;
        const float* wi = Wih + (size_t)Rrow * WIS + kg * KW;
        if constexpr (FP32W) {
            wf0 = load_f16v(wr +  0); wf1 = load_f16v(wr + 16);
            wf2 = load_f16v(wr + 32); wf3 = load_f16v(wr + 48);
            wf4 = load_f16v(wr + 64); wf5 = load_f16v(wr + 80);
            wf6 = load_f16v(wr + 96); wf7 = load_f16v(wr + 112);
            wx0 = load_f16v(wi + 0);  wx1 = load_f16v(wi + 16);
        } else {
            whA = load_pack32(wr +  0); whB = load_pack32(wr + 32);
            whC = load_pack32(wr + 64); whD = load_pack32(wr + 96);
            wiA = load_pack32(wi +  0); wiB = load_pack32(wi + 32);
            wiC = load_pack32(wi + 64); wiD = load_pack32(wi + 96);
        }
    }

    // ---- per-update-thread bias + cell state ----
    const int b0 = tid >> 5, uu = tid & 31;
    float biasv[4] = {0.f, 0.f, 0.f, 0.f};
    float cst = 0.0f;
    if (tid < SB * 32) {
        #pragma unroll
        for (int Gx = 0; Gx < 4; Gx++) {
            int RR = Gx * H_ + U0 + uu;
            if constexpr (LAYER == 0)
                biasv[Gx] = biasA[(size_t)(sb0 + b0) * G4 + RR];   // mc (includes biases)
            else
                biasv[Gx] = biasA[RR] + biasB[RR];                 // bih + bhh
        }
    }

    float acc[SB];
    for (int t = 0; t < T; t++) {
        // ---- stage x_t for the group's sub-batches ----
        constexpr int XV = KIN / 4;
        for (int idx = tid; idx < SB * XV; idx += 512) {
            int b = idx / XV, j = idx - b * XV;
            int sb = sb0 + b, bg = sb >> LAYER, k = sb & (DIL - 1);
            const float4* src = (const float4*)(x_in + ((size_t)bg * S_ + (size_t)t * DIL + k) * KIN);
            *(float4*)&lds_x[b][4 * j] = src[j];
        }
        __syncthreads();

        // ---- x-part of gates (overlaps the barrier wait below) ----
        #pragma unroll
        for (int b = 0; b < SB; b++) {
            const float4* xp = (const float4*)&lds_x[b][kg * KW];
            float a;
            if constexpr (FP32W)
                a = dotf(wx0, xp) + dotf(wx1, xp + 4);
            else
                a = dot32(wiA, xp) + dot32(wiB, xp + 8) +
                    dot32(wiC, xp + 16) + dot32(wiD, xp + 24);
            acc[b] = a;
        }

        // ---- wait for h_{t-1}, then recurrent part ----
        if (t > 0) {
            if (tid == 0) {
                int target = 16 * t;
                while (__hip_atomic_load(cgrp, __ATOMIC_RELAXED, SCOPE_AGENT) < target)
                    __builtin_amdgcn_s_sleep(1);
            }
            __syncthreads();
            float* hrd = h_buf + (size_t)((t - 1) & 1) * HB + (size_t)sb0 * H_;
            for (int idx = tid; idx < SB * H_; idx += 512) {
                lds_h[idx >> 9][idx & 511] =
                    __hip_atomic_load(hrd + idx, __ATOMIC_RELAXED, SCOPE_AGENT);
            }
            __syncthreads();
            #pragma unroll
            for (int b = 0; b < SB; b++) {
                const float4* hp = (const float4*)&lds_h[b][kg * 128];
                float a = acc[b];
                if constexpr (FP32W)
                    a += dotf(wf0, hp +  0) + dotf(wf1, hp +  4) +
                         dotf(wf2, hp +  8) + dotf(wf3, hp + 12) +
                         dotf(wf4, hp + 16) + dotf(wf5, hp + 20) +
                         dotf(wf6, hp + 24) + dotf(wf7, hp + 28);
                else
                    a += dot32(whA, hp) + dot32(whB, hp + 8) +
                         dot32(whC, hp + 16) + dot32(whD, hp + 24);
                acc[b] = a;
            }
        }

        // ---- reduce partials across the 4 k-quadrants ----
        #pragma unroll
        for (int b = 0; b < SB; b++) lds_p[b][r * 5 + kg] = acc[b];
        __syncthreads();

        // ---- gate nonlinearity + cell/hidden update (SB*32 threads) ----
        if (tid < SB * 32) {
            float gv[4];
            #pragma unroll
            for (int Gx = 0; Gx < 4; Gx++) {
                int rr = Gx * 32 + uu;
                gv[Gx] = lds_p[b0][rr * 5 + 0] + lds_p[b0][rr * 5 + 1] +
                         lds_p[b0][rr * 5 + 2] + lds_p[b0][rr * 5 + 3] + biasv[Gx];
            }
            float ci = sigm(gv[0]), cf = sigm(gv[1]);
            float cg = tanhfast(gv[2]), co = sigm(gv[3]);
            cst = cf * cst + ci * cg;
            float hv = co * tanhfast(cst);
            int sb = sb0 + b0, bg = sb >> LAYER, k = sb & (DIL - 1);
            __hip_atomic_store(h_buf + (size_t)(t & 1) * HB + (size_t)sb * H_ + U0 + uu,
                               hv, __ATOMIC_RELAXED, SCOPE_AGENT);
            float res;
            if constexpr (LAYER > 0) res = lds_x[b0][U0 + uu]; else res = 0.f;
            x_out[((size_t)bg * S_ + (size_t)t * DIL + k) * H_ + U0 + uu] = hv + res;
        }
        asm volatile("s_waitcnt vmcnt(0)" ::: "memory");
        __syncthreads();   // drains all waves' stores before the arrive
        if (tid == 0)
            __hip_atomic_fetch_add(cgrp, 1, __ATOMIC_RELAXED, SCOPE_AGENT);
    }
}

// ---------------------------------------------------------------------------
// out = x4 @ W_out.T + b_out   ([16384,512] x [512,128])
// ---------------------------------------------------------------------------
__global__ __launch_bounds__(256) void out_gemm(
    const float* __restrict__ x, const float* __restrict__ Wout,
    const float* __restrict__ bout, float* __restrict__ out)
{
    __shared__ __align__(16) float xs[8][H_];
    int tid = threadIdx.x;
    size_t tok0 = (size_t)blockIdx.x * 8;
    const float4* src = (const float4*)(x + tok0 * H_);
    for (int idx = tid; idx < 8 * H_ / 4; idx += 256)
        ((float4*)xs)[idx] = src[idx];
    __syncthreads();

    int col = tid & 127, th = tid >> 7;  // th: 0/1 -> tokens [0..3] / [4..7]
    int tb = th * 4;
    float a0 = 0.f, a1 = 0.f, a2 = 0.f, a3 = 0.f;
    const float4* w = (const float4*)(Wout + (size_t)col * H_);
    #pragma unroll 4
    for (int j = 0; j < H_ / 4; j++) {
        float4 wv = w[j];
        float4 x0 = ((const float4*)xs[tb + 0])[j];
        float4 x1 = ((const float4*)xs[tb + 1])[j];
        float4 x2 = ((const float4*)xs[tb + 2])[j];
        float4 x3 = ((const float4*)xs[tb + 3])[j];
        a0 = fmaf(wv.x, x0.x, a0); a0 = fmaf(wv.y, x0.y, a0); a0 = fmaf(wv.z, x0.z, a0); a0 = fmaf(wv.w, x0.w, a0);
        a1 = fmaf(wv.x, x1.x, a1); a1 = fmaf(wv.y, x1.y, a1); a1 = fmaf(wv.z, x1.z, a1); a1 = fmaf(wv.w, x1.w, a1);
        a2 = fmaf(wv.x, x2.x, a2); a2 = fmaf(wv.y, x2.y, a2); a2 = fmaf(wv.z, x2.z, a2); a2 = fmaf(wv.w, x2.w, a2);
        a3 = fmaf(wv.x, x3.x, a3); a3 = fmaf(wv.y, x3.y, a3); a3 = fmaf(wv.z, x3.z, a3); a3 = fmaf(wv.w, x3.w, a3);
    }
    float bo = bout[col];
    out[(tok0 + tb + 0) * FR + col] = a0 + bo;
    out[(tok0 + tb + 1) * FR + col] = a1 + bo;
    out[(tok0 + tb + 2) * FR + col] = a2 + bo;
    out[(tok0 + tb + 3) * FR + col] = a3 + bo;
}

// ---------------------------------------------------------------------------
extern "C" void kernel_launch(void* const* d_in, const int* in_sizes, int n_in,
                              void* d_out, int out_size, void* d_ws, size_t ws_size,
                              hipStream_t stream)
{
    const float* inputs = (const float*)d_in[0];
    const float* moods  = (const float*)d_in[1];
    const float* W_mood = (const float*)d_in[2];
    const float* b_mood = (const float*)d_in[3];
    const float* W_ih0  = (const float*)d_in[4];
    const float* W_hh0  = (const float*)d_in[5];
    const float* b_ih0  = (const float*)d_in[6];
    const float* b_hh0  = (const float*)d_in[7];
    const float* W_ih_r = (const float*)d_in[8];
    const float* W_hh_r = (const float*)d_in[9];
    const float* b_ih_r = (const float*)d_in[10];
    const float* b_hh_r = (const float*)d_in[11];
    const float* W_out  = (const float*)d_in[12];
    const float* b_out  = (const float*)d_in[13];

    float* ws = (float*)d_ws;
    float* mc = ws;                          // 16*2048        = 32768
    float* xA = ws + 32768;                  // 16*1024*512    = 8388608
    float* xB = xA + 8388608;
    float* hb = xB + 8388608;                // 2*128*512      = 131072
    int*  cnt = (int*)(hb + 131072);         // 4 layers x 16 groups x 32-int pad

    hipMemsetAsync(cnt, 0, 4 * CNT_PER_LAYER * sizeof(int), stream);
    mood_kernel<<<16, 256, 0, stream>>>(moods, W_mood, b_mood, W_ih0, b_ih0, b_hh0, mc);

    scan_kernel<0><<<256, 512, 0, stream>>>(inputs, xA, W_ih0, W_hh0, mc, nullptr, hb, cnt);
    scan_kernel<1><<<256, 512, 0, stream>>>(xA, xB, W_ih_r, W_hh_r,
                                            b_ih_r, b_hh_r, hb, cnt + CNT_PER_LAYER);
    scan_kernel<2><<<256, 512, 0, stream>>>(xB, xA, W_ih_r + (size_t)G4 * H_,
                                            W_hh_r + (size_t)G4 * H_,
                                            b_ih_r + G4, b_hh_r + G4, hb, cnt + 2 * CNT_PER_LAYER);
    scan_kernel<3><<<256, 512, 0, stream>>>(xA, xB, W_ih_r + (size_t)2 * G4 * H_,
                                            W_hh_r + (size_t)2 * G4 * H_,
                                            b_ih_r + 2 * G4, b_hh_r + 2 * G4, hb, cnt + 3 * CNT_PER_LAYER);

    out_gemm<<<2048, 256, 0, stream>>>(xB, W_out, b_out, (float*)d_out);
}

// Round 4
// 11714.308 us; speedup vs baseline: 7.1215x; 5.2021x over previous
//
#include <hip/hip_runtime.h>
#include <stdint.h>

#define DEVFN __device__ __forceinline__
#define SCOPE_AGENT __HIP_MEMORY_SCOPE_AGENT

static constexpr int B_ = 16;
static constexpr int S_ = 1024;
static constexpr int FR = 128;     // FULL_RANGE
static constexpr int MU = 32;      // MOOD_UNITS
static constexpr int H_ = 512;     // UNITS
static constexpr int G4 = 2048;    // 4*H

static constexpr int CNT_STRIDE = 32;                  // 128B-padded counters
static constexpr int CNT_PER_LAYER = 16 * CNT_STRIDE;  // 512 ints per layer

// packed-weight chunk counts (16B chunks of 8 bf16 weights)
static constexpr int NCH_WHH = 4 * 4 * 16 * 2048;          // 524288
static constexpr int NCH_WI0 = 4 * 4 * 2048;               // 32768
static constexpr int NCH_WIR = 3 * 4 * 16 * 2048;          // 393216
static constexpr int NCH_TOT = NCH_WHH + NCH_WI0 + NCH_WIR;

DEVFN float blo(uint32_t w) { return __uint_as_float(w << 16); }
DEVFN float bhi(uint32_t w) { return __uint_as_float(w & 0xffff0000u); }
DEVFN uint32_t pack_bf16(float a, float b) {
    uint32_t ua = __float_as_uint(a); ua += 0x7fffu + ((ua >> 16) & 1u);
    uint32_t ub = __float_as_uint(b); ub += 0x7fffu + ((ub >> 16) & 1u);
    return (ua >> 16) | (ub & 0xffff0000u);
}
DEVFN float sigm(float x) { return 1.0f / (1.0f + __expf(-x)); }
DEVFN float tanhfast(float x) {
    float e = __expf(2.0f * fabsf(x));
    float r = 1.0f - 2.0f / (e + 1.0f);   // e==inf -> r=1
    return copysignf(r, x);
}
// 1 packed chunk (8 bf16 weights for 8 consecutive k) . 8 floats
DEVFN float dot8a(uint4 w, const float4* __restrict__ p, float s) {
    float4 a = p[0], b = p[1];
    s = fmaf(blo(w.x), a.x, s); s = fmaf(bhi(w.x), a.y, s);
    s = fmaf(blo(w.y), a.z, s); s = fmaf(bhi(w.y), a.w, s);
    s = fmaf(blo(w.z), b.x, s); s = fmaf(bhi(w.z), b.y, s);
    s = fmaf(blo(w.w), b.z, s); s = fmaf(bhi(w.w), b.w, s);
    return s;
}

// ---------------------------------------------------------------------------
// mood: m = moods@W_mood.T + b_mood ; mc[b][row] = m@Wih0[:,128:160].T + bih0 + bhh0
// ---------------------------------------------------------------------------
__global__ __launch_bounds__(256) void mood_kernel(
    const float* __restrict__ moods, const float* __restrict__ W_mood,
    const float* __restrict__ b_mood, const float* __restrict__ W_ih0,
    const float* __restrict__ b_ih0, const float* __restrict__ b_hh0,
    float* __restrict__ mc)
{
    int b = blockIdx.x, tid = threadIdx.x;
    __shared__ float m[MU];
    if (tid < MU) {
        float s = b_mood[tid];
        #pragma unroll
        for (int j = 0; j < 4; j++) s += moods[b * 4 + j] * W_mood[tid * 4 + j];
        m[tid] = s;
    }
    __syncthreads();
    for (int row = tid; row < G4; row += 256) {
        float s = b_ih0[row] + b_hh0[row];
        const float* w = W_ih0 + (size_t)row * (FR + MU) + FR;
        #pragma unroll
        for (int u = 0; u < MU; u++) s += m[u] * w[u];
        mc[(size_t)b * G4 + row] = s;
    }
}

// ---------------------------------------------------------------------------
// Pre-pack weights to bf16 chunks, one thread per 16B chunk.
// pwh layout : [(l*4+kg)*16 + j][row 0..2047]   (k-range kg*128 + j*8 .. +8)
// pwi0       : [kg*4 + j][row]                  (k-range kg*32  + j*8 .. +8)
// pwir       : [(l*4+kg)*16 + j][row]           (l = layer-1)
// ---------------------------------------------------------------------------
__global__ __launch_bounds__(256) void pack_kernel(
    const float* __restrict__ W_hh0, const float* __restrict__ W_hh_r,
    const float* __restrict__ W_ih0, const float* __restrict__ W_ih_r,
    uint4* __restrict__ pwh, uint4* __restrict__ pwi0, uint4* __restrict__ pwir)
{
    int c = blockIdx.x * 256 + threadIdx.x;
    if (c >= NCH_TOT) return;
    const float* src;
    uint4* dst;
    if (c < NCH_WHH) {
        int l = c >> 17, kg = (c >> 15) & 3, j = (c >> 11) & 15, row = c & 2047;
        const float* W = (l == 0) ? W_hh0 : W_hh_r + (size_t)(l - 1) * G4 * H_;
        src = W + (size_t)row * H_ + kg * 128 + j * 8;
        dst = pwh + c;
    } else if (c < NCH_WHH + NCH_WI0) {
        int d = c - NCH_WHH;
        int kg = d >> 13, j = (d >> 11) & 3, row = d & 2047;
        src = W_ih0 + (size_t)row * (FR + MU) + kg * 32 + j * 8;
        dst = pwi0 + d;
    } else {
        int e = c - NCH_WHH - NCH_WI0;
        int l = e >> 17, kg = (e >> 15) & 3, j = (e >> 11) & 15, row = e & 2047;
        src = W_ih_r + (size_t)l * G4 * H_ + (size_t)row * H_ + kg * 128 + j * 8;
        dst = pwir + e;
    }
    uint4 o;
    o.x = pack_bf16(src[0], src[1]);
    o.y = pack_bf16(src[2], src[3]);
    o.z = pack_bf16(src[4], src[5]);
    o.w = pack_bf16(src[6], src[7]);
    *dst = o;
}

// ---------------------------------------------------------------------------
// Persistent dilated-LSTM scan. 16 groups x 16 WGs x 512 threads.
// Weights STREAMED from L2 each step (pre-packed bf16 chunks; one uint4 reg
// reused across SB sub-batches). No big register/LDS weight residency ->
// ~80 VGPR, no spill (R1-R3 failure: weight arrays -> scratch, 25-55 GB
// HBM re-reads/dispatch).
// x buffer is IN-PLACE: token t is staged to regs BEFORE our arrive(t); any
// writer of token t only writes after wait(t) sees all arrives -> ordered.
// x/h cross-WG traffic uses agent-scope atomics (no XCD-placement assumption).
// ---------------------------------------------------------------------------
template <int LAYER>
__global__ __launch_bounds__(512, 2) void scan_kernel(
    const float* __restrict__ x_in, float* __restrict__ x_out,
    const uint4* __restrict__ pwi, const uint4* __restrict__ pwh,
    const float* __restrict__ biasA, const float* __restrict__ biasB,
    float* __restrict__ h_buf, int* __restrict__ cnt)
{
    constexpr int DIL = 1 << LAYER;
    constexpr int SB = DIL;                  // sub-batches per group
    constexpr int T = S_ / DIL;
    constexpr int KIN = (LAYER == 0) ? FR : H_;
    constexpr int KW = KIN / 4;              // k-range per kg for Wih
    constexpr int NJX = KW / 8;              // Wih chunks/thread (4 or 16)
    constexpr int NJH = 16;                  // Whh chunks/thread
    constexpr int HB = 16 * SB * H_;         // floats per h_buf phase
    constexpr int XTOT = SB * KIN;           // staged floats per WG per step
    constexpr int XRS = (XTOT + 511) / 512;  // staged floats per thread
    constexpr int KSH = (LAYER == 0) ? 7 : 9;
    constexpr int LOFF = (LAYER == 0) ? 0 : (LAYER - 1);

    const int bid = blockIdx.x;
    const int g = bid & 15, wgi = bid >> 4;
    const int tid = threadIdx.x;
    const int kg = tid >> 7, r = tid & 127;
    const int U0 = wgi * 32;
    const int Rrow = (r >> 5) * H_ + U0 + (r & 31);   // global gate row
    const int sb0 = g * SB;

    __shared__ __align__(16) float lds_x[SB][KIN];
    __shared__ __align__(16) float lds_h[SB][H_];
    __shared__ float lds_p[SB][128 * 5];     // padded [128][5] partials

    int* cgrp = cnt + g * CNT_STRIDE;
    const uint4* WI = pwi + ((size_t)(LOFF * 4 + kg) * NJX) * G4 + Rrow;
    const uint4* WH = pwh + ((size_t)(LAYER * 4 + kg) * 16) * G4 + Rrow;

    // ---- per-update-thread bias + cell state ----
    const int b0 = tid >> 5, uu = tid & 31;
    float biasv[4] = {0.f, 0.f, 0.f, 0.f};
    float cst = 0.0f;
    if (tid < SB * 32) {
        #pragma unroll
        for (int Gx = 0; Gx < 4; Gx++) {
            int RR = Gx * H_ + U0 + uu;
            if constexpr (LAYER == 0)
                biasv[Gx] = biasA[(size_t)(sb0 + b0) * G4 + RR];   // mc (incl. biases)
            else
                biasv[Gx] = biasA[RR] + biasB[RR];
        }
    }

    // ---- prologue: stage token(0) into regs ----
    float xsr[XRS];
    #pragma unroll
    for (int rr = 0; rr < XRS; rr++) {
        int idx = tid + rr * 512;
        if (idx < XTOT) {
            int b = idx >> KSH, off = idx & (KIN - 1);
            int sb = sb0 + b, bg = sb >> LAYER, k = sb & (DIL - 1);
            xsr[rr] = __hip_atomic_load(
                x_in + ((size_t)bg * S_ + k) * KIN + off,
                __ATOMIC_RELAXED, SCOPE_AGENT);
        }
    }

    float acc[SB];
    for (int t = 0; t < T; t++) {
        // ---- staged regs -> LDS ----
        #pragma unroll
        for (int rr = 0; rr < XRS; rr++) {
            int idx = tid + rr * 512;
            if (idx < XTOT) lds_x[idx >> KSH][idx & (KIN - 1)] = xsr[rr];
        }
        __syncthreads();

        // ---- issue token(t+1) loads (completes during this step; must be
        //      before our arrive(t) for the in-place ordering argument) ----
        if (t + 1 < T) {
            #pragma unroll
            for (int rr = 0; rr < XRS; rr++) {
                int idx = tid + rr * 512;
                if (idx < XTOT) {
                    int b = idx >> KSH, off = idx & (KIN - 1);
                    int sb = sb0 + b, bg = sb >> LAYER, k = sb & (DIL - 1);
                    xsr[rr] = __hip_atomic_load(
                        x_in + ((size_t)bg * S_ + (size_t)(t + 1) * DIL + k) * KIN + off,
                        __ATOMIC_RELAXED, SCOPE_AGENT);
                }
            }
        }

        // ---- x-part: stream Wih chunks, reuse each across SB ----
        #pragma unroll
        for (int b = 0; b < SB; b++) acc[b] = 0.f;
        #pragma unroll 4
        for (int j = 0; j < NJX; j++) {
            uint4 w = WI[(size_t)j * G4];
            #pragma unroll
            for (int b = 0; b < SB; b++)
                acc[b] = dot8a(w, (const float4*)&lds_x[b][kg * KW + j * 8], acc[b]);
        }

        // ---- wait for h(t-1), then recurrent part (stream Whh) ----
        if (t > 0) {
            if (tid == 0) {
                int target = 16 * t;
                while (__hip_atomic_load(cgrp, __ATOMIC_RELAXED, SCOPE_AGENT) < target)
                    __builtin_amdgcn_s_sleep(1);
            }
            __syncthreads();
            float* hrd = h_buf + (size_t)((t - 1) & 1) * HB + (size_t)sb0 * H_;
            for (int idx = tid; idx < SB * H_; idx += 512)
                lds_h[idx >> 9][idx & 511] =
                    __hip_atomic_load(hrd + idx, __ATOMIC_RELAXED, SCOPE_AGENT);
            __syncthreads();
            #pragma unroll 4
            for (int j = 0; j < NJH; j++) {
                uint4 w = WH[(size_t)j * G4];
                #pragma unroll
                for (int b = 0; b < SB; b++)
                    acc[b] = dot8a(w, (const float4*)&lds_h[b][kg * 128 + j * 8], acc[b]);
            }
        }

        // ---- reduce partials across the 4 k-quadrants ----
        #pragma unroll
        for (int b = 0; b < SB; b++) lds_p[b][r * 5 + kg] = acc[b];
        __syncthreads();

        // ---- gate nonlinearity + cell/hidden update (SB*32 threads) ----
        if (tid < SB * 32) {
            float gv[4];
            #pragma unroll
            for (int Gx = 0; Gx < 4; Gx++) {
                int rr = Gx * 32 + uu;
                gv[Gx] = lds_p[b0][rr * 5 + 0] + lds_p[b0][rr * 5 + 1] +
                         lds_p[b0][rr * 5 + 2] + lds_p[b0][rr * 5 + 3] + biasv[Gx];
            }
            float ci = sigm(gv[0]), cf = sigm(gv[1]);
            float cg = tanhfast(gv[2]), co = sigm(gv[3]);
            cst = cf * cst + ci * cg;
            float hv = co * tanhfast(cst);
            int sb = sb0 + b0, bg = sb >> LAYER, k = sb & (DIL - 1);
            __hip_atomic_store(h_buf + (size_t)(t & 1) * HB + (size_t)sb * H_ + U0 + uu,
                               hv, __ATOMIC_RELAXED, SCOPE_AGENT);
            float res;
            if constexpr (LAYER > 0) res = lds_x[b0][U0 + uu]; else res = 0.f;
            __hip_atomic_store(x_out + ((size_t)bg * S_ + (size_t)t * DIL + k) * H_ + U0 + uu,
                               hv + res, __ATOMIC_RELAXED, SCOPE_AGENT);
        }
        asm volatile("s_waitcnt vmcnt(0)" ::: "memory");
        __syncthreads();   // all stores drained before the arrive
        if (tid == 0)
            __hip_atomic_fetch_add(cgrp, 1, __ATOMIC_RELAXED, SCOPE_AGENT);
    }
}

// ---------------------------------------------------------------------------
// out = x @ W_out.T + b_out   ([16384,512] x [512,128])
// ---------------------------------------------------------------------------
__global__ __launch_bounds__(256) void out_gemm(
    const float* __restrict__ x, const float* __restrict__ Wout,
    const float* __restrict__ bout, float* __restrict__ out)
{
    __shared__ __align__(16) float xs[8][H_];
    int tid = threadIdx.x;
    size_t tok0 = (size_t)blockIdx.x * 8;
    const float4* src = (const float4*)(x + tok0 * H_);
    for (int idx = tid; idx < 8 * H_ / 4; idx += 256)
        ((float4*)xs)[idx] = src[idx];
    __syncthreads();

    int col = tid & 127, th = tid >> 7;
    int tb = th * 4;
    float a0 = 0.f, a1 = 0.f, a2 = 0.f, a3 = 0.f;
    const float4* w = (const float4*)(Wout + (size_t)col * H_);
    #pragma unroll 4
    for (int j = 0; j < H_ / 4; j++) {
        float4 wv = w[j];
        float4 x0 = ((const float4*)xs[tb + 0])[j];
        float4 x1 = ((const float4*)xs[tb + 1])[j];
        float4 x2 = ((const float4*)xs[tb + 2])[j];
        float4 x3 = ((const float4*)xs[tb + 3])[j];
        a0 = fmaf(wv.x, x0.x, a0); a0 = fmaf(wv.y, x0.y, a0); a0 = fmaf(wv.z, x0.z, a0); a0 = fmaf(wv.w, x0.w, a0);
        a1 = fmaf(wv.x, x1.x, a1); a1 = fmaf(wv.y, x1.y, a1); a1 = fmaf(wv.z, x1.z, a1); a1 = fmaf(wv.w, x1.w, a1);
        a2 = fmaf(wv.x, x2.x, a2); a2 = fmaf(wv.y, x2.y, a2); a2 = fmaf(wv.z, x2.z, a2); a2 = fmaf(wv.w, x2.w, a2);
        a3 = fmaf(wv.x, x3.x, a3); a3 = fmaf(wv.y, x3.y, a3); a3 = fmaf(wv.z, x3.z, a3); a3 = fmaf(wv.w, x3.w, a3);
    }
    float bo = bout[col];
    out[(tok0 + tb + 0) * FR + col] = a0 + bo;
    out[(tok0 + tb + 1) * FR + col] = a1 + bo;
    out[(tok0 + tb + 2) * FR + col] = a2 + bo;
    out[(tok0 + tb + 3) * FR + col] = a3 + bo;
}

// ---------------------------------------------------------------------------
extern "C" void kernel_launch(void* const* d_in, const int* in_sizes, int n_in,
                              void* d_out, int out_size, void* d_ws, size_t ws_size,
                              hipStream_t stream)
{
    const float* inputs = (const float*)d_in[0];
    const float* moods  = (const float*)d_in[1];
    const float* W_mood = (const float*)d_in[2];
    const float* b_mood = (const float*)d_in[3];
    const float* W_ih0  = (const float*)d_in[4];
    const float* W_hh0  = (const float*)d_in[5];
    const float* b_ih0  = (const float*)d_in[6];
    const float* b_hh0  = (const float*)d_in[7];
    const float* W_ih_r = (const float*)d_in[8];
    const float* W_hh_r = (const float*)d_in[9];
    const float* b_ih_r = (const float*)d_in[10];
    const float* b_hh_r = (const float*)d_in[11];
    const float* W_out  = (const float*)d_in[12];
    const float* b_out  = (const float*)d_in[13];

    float* ws = (float*)d_ws;
    float* mc  = ws;                         // 32768 floats
    float* xA  = ws + 32768;                 // 16*1024*512 = 8388608 (in-place x)
    float* hb  = xA + 8388608;               // 131072
    int*   cnt = (int*)(hb + 131072);        // 2048 ints
    uint4* pwh  = (uint4*)(cnt + 2048);      // 524288 uint4
    uint4* pwi0 = pwh + NCH_WHH;             // 32768 uint4
    uint4* pwir = pwi0 + NCH_WI0;            // 393216 uint4
    // total ~49.5 MB (< R3's proven 67.6 MB footprint)

    hipMemsetAsync(cnt, 0, 2048 * sizeof(int), stream);
    mood_kernel<<<16, 256, 0, stream>>>(moods, W_mood, b_mood, W_ih0, b_ih0, b_hh0, mc);
    pack_kernel<<<(NCH_TOT + 255) / 256, 256, 0, stream>>>(
        W_hh0, W_hh_r, W_ih0, W_ih_r, pwh, pwi0, pwir);

    scan_kernel<0><<<256, 512, 0, stream>>>(inputs, xA, pwi0, pwh, mc, nullptr, hb, cnt);
    scan_kernel<1><<<256, 512, 0, stream>>>(xA, xA, pwir, pwh,
                                            b_ih_r, b_hh_r, hb, cnt + CNT_PER_LAYER);
    scan_kernel<2><<<256, 512, 0, stream>>>(xA, xA, pwir, pwh,
                                            b_ih_r + G4, b_hh_r + G4, hb, cnt + 2 * CNT_PER_LAYER);
    scan_kernel<3><<<256, 512, 0, stream>>>(xA, xA, pwir, pwh,
                                            b_ih_r + 2 * G4, b_hh_r + 2 * G4, hb, cnt + 3 * CNT_PER_LAYER);

    out_gemm<<<2048, 256, 0, stream>>>(xA, W_out, b_out, (float*)d_out);
}